// Round 1
// 482.490 us; speedup vs baseline: 1.0122x; 1.0122x over previous
//
#include <hip/hip_runtime.h>
#include <math.h>

// GCN: h = elu(D^-1/2 (A+I) D^-1/2 (h W) + b [+ resid])
// N=100000 nodes, E=1600000 edges, 128 features per layer.
//
// R8 changes vs R7: aggregate_kernel datapath rewrite.
//  - R7 evidence: aggregate = 3x75.5us (46% of total), VALUBusy 52%,
//    hbm 46%, MfmaUtil 0 -> mixed VALU/latency regime, neither saturated.
//  - 16B/lane gathers (dwordx4, quarter-split): 4 edges per VMEM instr
//    (was 2), halving VMEM issue + TA pressure.
//  - Remainder loop eliminated: lanes >= cnt carry pk=0 -> row0, w=0;
//    8-edge body runs unconditionally (branch-free inner loop).
//  - bf16 unpack as (u&0xffff0000 | u<<16) in-place f32; 32-bit
//    pre-shifted byte offsets shfl'd directly (no 64-bit addr chains).
//  - Epilogue all-64-lane: quarter q writes 2 of its 8 columns ->
//    2 expm1f wide instead of 4 expm1f on half the lanes.
//  - Nontemporal resid/out/colw: protect the 25.6MB gather table in L2
//    from 102MB of zero-reuse stream traffic.

#define NFEAT 128
#define LDSP 136   // LDS row pitch in shorts (128 + 8 pad)
#define BSH 9      // bucket shift: 512 nodes/bucket
#define BWID 512

typedef short short8 __attribute__((ext_vector_type(8)));
typedef float f32x4 __attribute__((ext_vector_type(4)));
typedef float f32x2 __attribute__((ext_vector_type(2)));
typedef int i32x4 __attribute__((ext_vector_type(4)));

static __device__ __forceinline__ unsigned short f2bf(float f) {
  union { float f; unsigned int u; } v; v.f = f;
  unsigned int r = v.u + 0x7fffu + ((v.u >> 16) & 1u);  // RNE (finite values)
  return (unsigned short)(r >> 16);
}
static __device__ __forceinline__ float bf2f(unsigned short b) {
  union { unsigned int u; float f; } v; v.u = ((unsigned int)b) << 16;
  return v.f;
}

// ---------------- GEMM body (LDS-staged MFMA) ----------------
// hW_bf16[n,128] = h[n,128] @ W. 64 nodes/block, operand-swapped MFMA so
// each lane stores contiguous ushort4 runs of its own node row.
static __device__ __forceinline__ void gemm_body(
    int gblk, const float* __restrict__ h, const unsigned short* __restrict__ Wt,
    unsigned short* __restrict__ out, int n, unsigned short* lds) {
  int t = threadIdx.x;
  int block0 = gblk * 64;

  const f32x4* h4 = (const f32x4*)h;
  #pragma unroll
  for (int i = 0; i < 8; ++i) {
    int idx = t + 256 * i;          // 0..2047
    int r = idx >> 5, c = idx & 31; // row, float4-col
    int grow = block0 + r; if (grow >= n) grow = n - 1;
    f32x4 v = __builtin_nontemporal_load(&h4[(size_t)grow * 32 + c]);
    ushort4 b;
    b.x = f2bf(v.x); b.y = f2bf(v.y); b.z = f2bf(v.z); b.w = f2bf(v.w);
    *(ushort4*)&lds[r * LDSP + c * 4] = b;
  }
  __syncthreads();

  int lane = t & 63, wave = t >> 6;
  int row16 = lane & 15;
  int kgrp = lane >> 4;

  short8 afrag[4];
  #pragma unroll
  for (int ks = 0; ks < 4; ++ks)
    afrag[ks] =
        *(const short8*)&lds[(wave * 16 + row16) * LDSP + ks * 32 + kgrp * 8];

  f32x4 acc[8];
  #pragma unroll
  for (int ct = 0; ct < 8; ++ct) {
    acc[ct] = (f32x4){0.0f, 0.0f, 0.0f, 0.0f};
    const short8* wrow =
        (const short8*)(Wt + (size_t)(ct * 16 + row16) * NFEAT);
    #pragma unroll
    for (int ks = 0; ks < 4; ++ks) {
      acc[ct] = __builtin_amdgcn_mfma_f32_16x16x32_bf16(
          wrow[ks * 4 + kgrp], afrag[ks], acc[ct], 0, 0, 0);
    }
  }

  int orow = block0 + wave * 16 + row16;
  if (orow < n) {
    unsigned short* op = out + (size_t)orow * NFEAT + kgrp * 4;
    #pragma unroll
    for (int ct = 0; ct < 8; ++ct) {
      ushort4 o;
      o.x = f2bf(acc[ct][0]); o.y = f2bf(acc[ct][1]);
      o.z = f2bf(acc[ct][2]); o.w = f2bf(acc[ct][3]);
      *(ushort4*)(op + ct * 16) = o;
    }
  }
}

__global__ __launch_bounds__(256) void gemm_mfma_kernel(
    const float* __restrict__ h, const unsigned short* __restrict__ Wt,
    unsigned short* __restrict__ out, int n) {
  __shared__ int lds_i[64 * LDSP / 2];
  gemm_body(blockIdx.x, h, Wt, out, n, (unsigned short*)lds_i);
}

// gemm0 fused with Pass A (bucket histogram) — independent work.
__global__ __launch_bounds__(256) void fused_g0_hist_kernel(
    const float* __restrict__ x, const unsigned short* __restrict__ Wt0,
    unsigned short* __restrict__ hWb, int n, int gb,
    const int4* __restrict__ dst4, int* __restrict__ bcnt, int e4, int nbuc) {
  __shared__ int lds_i[64 * LDSP / 2];
  int t = threadIdx.x;
  if ((int)blockIdx.x < gb) {
    gemm_body(blockIdx.x, x, Wt0, hWb, n, (unsigned short*)lds_i);
  } else {
    int* hist = lds_i;
    hist[t] = 0;
    __syncthreads();
    int base = ((int)blockIdx.x - gb) * 1024;
    #pragma unroll
    for (int i = 0; i < 4; ++i) {
      int idx = base + t + 256 * i;
      if (idx < e4) {
        int4 d = dst4[idx];
        atomicAdd(&hist[d.x >> BSH], 1);
        atomicAdd(&hist[d.y >> BSH], 1);
        atomicAdd(&hist[d.z >> BSH], 1);
        atomicAdd(&hist[d.w >> BSH], 1);
      }
    }
    __syncthreads();
    int h = hist[t];
    if (t < nbuc && h) atomicAdd(&bcnt[t], h);
  }
}

// Pass B: exclusive scan of bucket counts (nbuc <= 256), init gcur, rowp[n]=E
__global__ __launch_bounds__(256) void scan_buckets_kernel(
    const int* __restrict__ bcnt, int* __restrict__ boff,
    int* __restrict__ gcur, int* __restrict__ rowp, int nbuc, int n, int e) {
  __shared__ int wsum[4];
  int t = threadIdx.x, lane = t & 63, wid = t >> 6;
  int v = (t < nbuc) ? bcnt[t] : 0;
  int s = v;
  #pragma unroll
  for (int off = 1; off < 64; off <<= 1) {
    int u = __shfl_up(s, off, 64);
    if (lane >= off) s += u;
  }
  if (lane == 63) wsum[wid] = s;
  __syncthreads();
  int add = 0;
  for (int w = 0; w < wid; ++w) add += wsum[w];
  int incl = add + s;
  if (t < nbuc) { boff[t] = incl - v; gcur[t] = incl - v; }
  if (t == nbuc - 1) boff[nbuc] = incl;  // == E
  if (t == 0) rowp[n] = e;
}

// Pass C: scatter (dst,src) u64 into bucket-major ebuf, block-chunked.
__global__ __launch_bounds__(256) void bucket_scatter_kernel(
    const int4* __restrict__ src4, const int4* __restrict__ dst4,
    int* __restrict__ gcur, unsigned long long* __restrict__ ebuf, int e4) {
  __shared__ int hist[256];
  __shared__ int cbase[256];
  __shared__ int cur[256];
  int t = threadIdx.x;
  hist[t] = 0; cur[t] = 0;
  __syncthreads();
  int base = blockIdx.x * 1024;
  int4 dv[4], sv[4];
  bool val[4];
  #pragma unroll
  for (int i = 0; i < 4; ++i) {
    int idx = base + t + 256 * i;
    val[i] = idx < e4;
    if (val[i]) {
      dv[i] = dst4[idx];
      sv[i] = src4[idx];
      atomicAdd(&hist[dv[i].x >> BSH], 1);
      atomicAdd(&hist[dv[i].y >> BSH], 1);
      atomicAdd(&hist[dv[i].z >> BSH], 1);
      atomicAdd(&hist[dv[i].w >> BSH], 1);
    }
  }
  __syncthreads();
  int h = hist[t];
  if (h) cbase[t] = atomicAdd(&gcur[t], h);  // hist[t]==0 for t>=nbuc
  __syncthreads();
  #pragma unroll
  for (int i = 0; i < 4; ++i) {
    if (val[i]) {
      int d, s, b, p;
      d = dv[i].x; s = sv[i].x; b = d >> BSH;
      p = cbase[b] + atomicAdd(&cur[b], 1);
      ebuf[p] = ((unsigned long long)(unsigned)d << 32) | (unsigned)s;
      d = dv[i].y; s = sv[i].y; b = d >> BSH;
      p = cbase[b] + atomicAdd(&cur[b], 1);
      ebuf[p] = ((unsigned long long)(unsigned)d << 32) | (unsigned)s;
      d = dv[i].z; s = sv[i].z; b = d >> BSH;
      p = cbase[b] + atomicAdd(&cur[b], 1);
      ebuf[p] = ((unsigned long long)(unsigned)d << 32) | (unsigned)s;
      d = dv[i].w; s = sv[i].w; b = d >> BSH;
      p = cbase[b] + atomicAdd(&cur[b], 1);
      ebuf[p] = ((unsigned long long)(unsigned)d << 32) | (unsigned)s;
    }
  }
}

// Pass D1: per-bucket degree hist (LDS) + local scan -> rowp, dinv.
__global__ __launch_bounds__(256) void bucket_deg_kernel(
    const unsigned long long* __restrict__ ebuf, const int* __restrict__ boff,
    int* __restrict__ rowp, float* __restrict__ dinv, int n) {
  __shared__ int deg[BWID];
  __shared__ int wsum[4];
  int t = threadIdx.x;
  int b = blockIdx.x, node0 = b << BSH;
  deg[t] = 0; deg[t + 256] = 0;
  __syncthreads();
  int ebeg = boff[b], eend = boff[b + 1];
  for (int i = ebeg + t; i < eend; i += 256) {
    int d = (int)(ebuf[i] >> 32);
    atomicAdd(&deg[d - node0], 1);
  }
  __syncthreads();
  int d0 = deg[2 * t], d1 = deg[2 * t + 1];
  int s = d0 + d1;
  int lane = t & 63, wid = t >> 6;
  int sc = s;
  #pragma unroll
  for (int off = 1; off < 64; off <<= 1) {
    int u = __shfl_up(sc, off, 64);
    if (lane >= off) sc += u;
  }
  if (lane == 63) wsum[wid] = sc;
  __syncthreads();
  int add = 0;
  for (int w = 0; w < wid; ++w) add += wsum[w];
  int excl = ebeg + add + sc - s;  // rowp of node 2t in this bucket
  int node = node0 + 2 * t;
  if (node < n) {
    rowp[node] = excl;
    dinv[node] = rsqrtf(1.0f + (float)d0);
  }
  if (node + 1 < n) {
    rowp[node + 1] = excl + d0;
    dinv[node + 1] = rsqrtf(1.0f + (float)d1);
  }
}

// Pass D2: per-bucket fine scatter into colw (writes confined to the
// bucket's ~32KB region -> one block/XCD -> L2 lines merge fully).
__global__ __launch_bounds__(256) void bucket_fill_kernel(
    const unsigned long long* __restrict__ ebuf, const int* __restrict__ boff,
    const int* __restrict__ rowp, const float* __restrict__ dinv,
    unsigned int* __restrict__ colw, int n) {
  __shared__ int cur[BWID];
  int t = threadIdx.x;
  int b = blockIdx.x, node0 = b << BSH;
  for (int k = t; k < BWID; k += 256) {
    int node = node0 + k;
    cur[k] = (node < n) ? rowp[node] : 0;
  }
  __syncthreads();
  int ebeg = boff[b], eend = boff[b + 1];
  for (int i = ebeg + t; i < eend; i += 256) {
    unsigned long long p = ebuf[i];
    int d = (int)(p >> 32);
    int s = (int)(unsigned int)p;
    float w = dinv[s] * dinv[d];
    unsigned int wq = (unsigned int)(w * 32767.0f + 0.5f);
    int pos = atomicAdd(&cur[d - node0], 1);
    colw[pos] = ((unsigned int)s << 15) | wq;
  }
}

// W fp32 [k][n] -> Wt bf16 [n][k]  (128x128), 3 weights in one launch
__global__ __launch_bounds__(256) void wprep_kernel(
    const float* __restrict__ W0, const float* __restrict__ W1,
    const float* __restrict__ W2, unsigned short* __restrict__ Wt0,
    unsigned short* __restrict__ Wt1, unsigned short* __restrict__ Wt2) {
  int which = blockIdx.x >> 6;
  int i = (blockIdx.x & 63) * 256 + threadIdx.x;
  int nn = i >> 7, k = i & 127;
  const float* W = which == 0 ? W0 : (which == 1 ? W1 : W2);
  unsigned short* Wt = which == 0 ? Wt0 : (which == 1 ? Wt1 : Wt2);
  Wt[nn * 128 + k] = f2bf(W[k * 128 + nn]);
}

// ---------------- Aggregate ----------------
// One wave per node, quarter-split gathers: lanes (q*16..q*16+15) handle
// edge j+q; each lane loads 16B (dwordx4) of a row -> 4 edges per VMEM
// instruction. Lanes >= cnt carry pk=0 (row 0, weight 0) so the 8-edge
// body runs unconditionally (no remainder loop). All __shfl in uniform
// control flow.
__global__ __launch_bounds__(256) void aggregate_kernel(
    const unsigned short* __restrict__ hWb, const int* __restrict__ row_ptr,
    const unsigned int* __restrict__ colw, const float* __restrict__ dinv,
    const float* __restrict__ bias, const float* __restrict__ resid,
    float* __restrict__ out, int n) {
  int node = blockIdx.x * 4 + (threadIdx.x >> 6);
  int lane = threadIdx.x & 63;
  if (node >= n) return;  // wave-uniform
  int q = lane >> 4;      // quarter: which edge of the 4-pack
  int l15 = lane & 15;
  int lb = l15 * 16;      // byte offset within a 256B row
  const char* hWbc = (const char*)hWb;
  int beg = row_ptr[node], end = row_ptr[node + 1];
  const float WQI = 1.0f / 32767.0f;

  float acc[8];
  #pragma unroll
  for (int k = 0; k < 8; ++k) acc[k] = 0.0f;

  for (int cbeg = beg; cbeg < end; cbeg += 64) {
    int cnt = end - cbeg; if (cnt > 64) cnt = 64;
    unsigned int pk = 0;                 // lanes >= cnt: row 0, weight 0
    if (lane < cnt) pk = __builtin_nontemporal_load(&colw[cbeg + lane]);
    unsigned int bo = (pk >> 15) << 8;   // row byte offset (s * 256)
    float wv = (float)(pk & 0x7fffu) * WQI;
    for (int j = 0; j < cnt; j += 8) {
      unsigned int boa = (unsigned int)__shfl((int)bo, j + q, 64);
      unsigned int bob = (unsigned int)__shfl((int)bo, j + 4 + q, 64);
      float wa = __shfl(wv, j + q, 64);
      float wb = __shfl(wv, j + 4 + q, 64);
      i32x4 pa = *(const i32x4*)(hWbc + (boa + (unsigned int)lb));
      i32x4 pb = *(const i32x4*)(hWbc + (bob + (unsigned int)lb));
      #pragma unroll
      for (int m = 0; m < 4; ++m) {
        int ua = pa[m];
        acc[2 * m]     += wa * __int_as_float(ua << 16);
        acc[2 * m + 1] += wa * __int_as_float(ua & 0xffff0000);
      }
      #pragma unroll
      for (int m = 0; m < 4; ++m) {
        int ub = pb[m];
        acc[2 * m]     += wb * __int_as_float(ub << 16);
        acc[2 * m + 1] += wb * __int_as_float(ub & 0xffff0000);
      }
    }
  }

  // reduce across the 4 quarters: all lanes end with full sums for their
  // 8 columns [l15*8, l15*8+8)
  #pragma unroll
  for (int k = 0; k < 8; ++k) {
    acc[k] += __shfl_xor(acc[k], 16, 64);
    acc[k] += __shfl_xor(acc[k], 32, 64);
  }

  // epilogue, all 64 lanes active: quarter q owns columns 2q, 2q+1 of
  // this lane's 8-column slice
  float sx = 0.0f, sy = 0.0f;
  #pragma unroll
  for (int k = 0; k < 4; ++k) {
    if (q == k) { sx = acc[2 * k]; sy = acc[2 * k + 1]; }
  }
  float di = dinv[node];
  float dii = di * di;
  unsigned int su =
      *(const unsigned int*)(hWbc + (size_t)node * 256 + (unsigned)(lb + q * 4));
  f32x2 bv = ((const f32x2*)bias)[l15 * 4 + q];
  float ax = sx + dii * __int_as_float((int)(su << 16)) + bv.x;
  float ay = sy + dii * __int_as_float((int)(su & 0xffff0000u)) + bv.y;
  size_t oidx = (size_t)node * 64 + (unsigned)(l15 * 4 + q);
  if (resid != nullptr) {
    f32x2 r = __builtin_nontemporal_load(&((const f32x2*)resid)[oidx]);
    ax += r.x; ay += r.y;
  }
  f32x2 o;
  o.x = ax > 0.0f ? ax : expm1f(ax);
  o.y = ay > 0.0f ? ay : expm1f(ay);
  __builtin_nontemporal_store(o, &((f32x2*)out)[oidx]);
}

extern "C" void kernel_launch(void* const* d_in, const int* in_sizes, int n_in,
                              void* d_out, int out_size, void* d_ws, size_t ws_size,
                              hipStream_t stream) {
  const float* x  = (const float*)d_in[0];
  const int* eidx = (const int*)d_in[1];
  const float* W0 = (const float*)d_in[2];
  const float* b0 = (const float*)d_in[3];
  const float* W1 = (const float*)d_in[4];
  const float* b1 = (const float*)d_in[5];
  const float* W2 = (const float*)d_in[6];
  const float* b2 = (const float*)d_in[7];
  float* outp = (float*)d_out;

  const int N = in_sizes[0] / NFEAT;   // 100000
  const int E = in_sizes[1] / 2;       // 1600000 (divisible by 4)
  const int* src = eidx;
  const int* dst = eidx + E;
  const int NBUC = (N + BWID - 1) >> BSH;  // 196
  const int e4 = E / 4;

  // workspace layout (all chunk sizes 1KB-multiples)
  const size_t S1 = 401408;                   // > (N+1)*4
  const size_t SBK = 1024;                    // > (NBUC+1)*4
  const size_t SW = 32768;                    // 128*128*2
  const size_t SE = (size_t)E * 4;            // 6.4 MB packed edges
  const size_t SEB = (size_t)E * 8;           // 12.8 MB bucketed (dst,src)
  const size_t SH = (size_t)N * NFEAT * 2;    // 25.6 MB bf16 features
  const size_t SF = (size_t)N * NFEAT * 4;    // 51.2 MB fp32 features
  char* p = (char*)d_ws;
  float* dinv   = (float*)p;            p += S1;
  int*   rowp   = (int*)p;              p += S1;
  int*   bcnt   = (int*)p;              p += SBK;
  int*   boff   = (int*)p;              p += SBK;
  int*   gcur   = (int*)p;              p += SBK;
  unsigned short* Wt0 = (unsigned short*)p;  p += SW;
  unsigned short* Wt1 = (unsigned short*)p;  p += SW;
  unsigned short* Wt2 = (unsigned short*)p;  p += SW;
  unsigned int* colw = (unsigned int*)p; p += SE;
  unsigned long long* ebuf = (unsigned long long*)p; p += SEB;
  unsigned short* hWb = (unsigned short*)p;  p += SH;
  float* hA     = (float*)p;            p += SF;
  float* hB     = (float*)p;            p += SF;

  int gemm_blocks = (N + 63) / 64;        // 1563
  int cbk = (e4 + 1023) / 1024;           // 391 (4096 edges/block)
  int agg_blocks = (N + 3) / 4;

  // ---- prep + fused {gemm0, Pass A} ----
  wprep_kernel<<<192, 256, 0, stream>>>(W0, W1, W2, Wt0, Wt1, Wt2);
  hipMemsetAsync(bcnt, 0, (size_t)NBUC * 4, stream);
  fused_g0_hist_kernel<<<gemm_blocks + cbk, 256, 0, stream>>>(
      x, Wt0, hWb, N, gemm_blocks, (const int4*)dst, bcnt, e4, NBUC);

  // ---- bucketed CSR build ----
  scan_buckets_kernel<<<1, 256, 0, stream>>>(bcnt, boff, gcur, rowp,
                                             NBUC, N, E);
  bucket_scatter_kernel<<<cbk, 256, 0, stream>>>(
      (const int4*)src, (const int4*)dst, gcur, ebuf, e4);
  bucket_deg_kernel<<<NBUC, 256, 0, stream>>>(ebuf, boff, rowp, dinv, N);
  bucket_fill_kernel<<<NBUC, 256, 0, stream>>>(ebuf, boff, rowp, dinv,
                                               colw, N);

  // ---- layer 0 aggregate (gemm0 already done) ----
  aggregate_kernel<<<agg_blocks, 256, 0, stream>>>(hWb, rowp, colw, dinv,
                                                   b0, nullptr, hA, N);
  // ---- layer 1 ----
  gemm_mfma_kernel<<<gemm_blocks, 256, 0, stream>>>(hA, Wt1, hWb, N);
  aggregate_kernel<<<agg_blocks, 256, 0, stream>>>(hWb, rowp, colw, dinv,
                                                   b1, hA, hB, N);
  // ---- layer 2, write d_out ----
  gemm_mfma_kernel<<<gemm_blocks, 256, 0, stream>>>(hB, Wt2, hWb, N);
  aggregate_kernel<<<agg_blocks, 256, 0, stream>>>(hWb, rowp, colw, dinv,
                                                   b2, hB, outp, N);
}

// Round 2
// 464.685 us; speedup vs baseline: 1.0510x; 1.0383x over previous
//
#include <hip/hip_runtime.h>
#include <math.h>

// GCN: h = elu(D^-1/2 (A+I) D^-1/2 (h W) + b [+ resid])
// N=100000 nodes, E=1600000 edges, 128 features per layer.
//
// R9 changes vs R8: aggregate MLP (memory-level-parallelism) deepening.
//  - R8 evidence: halving VMEM instrs + VALU cut -> dur unchanged
//    (75.5us), VALUBusy 48%, occupancy 75%, FETCH at the per-XCD
//    compulsory floor (~205MB). Neither pipe saturated -> latency-bound
//    with ~2 outstanding gathers/wave (R8 issued only 2 loads per
//    j-step; R7 had 4 -> explains R8's null result).
//  - Inner loop now steps 16 edges: 4 independent dwordx4 gathers
//    issued back-to-back (all addresses ready after the chunk's colw
//    load) -> 4+ outstanding per wave.
//  - Self-row, resid, bias loads hoisted ahead of the edge loop ->
//    3 more independent loads in flight during the gather phase.
//  - Unpack-FMA converted to f32x2 packed math (v_pk_fma_f32): halves
//    FMA issue slots.
//  - If this is null too, the 3.6 TB/s is a fabric ceiling for random
//    256B L2-miss traffic -> only byte reduction (fp8) remains.

#define NFEAT 128
#define LDSP 136   // LDS row pitch in shorts (128 + 8 pad)
#define BSH 9      // bucket shift: 512 nodes/bucket
#define BWID 512

typedef short short8 __attribute__((ext_vector_type(8)));
typedef float f32x4 __attribute__((ext_vector_type(4)));
typedef float f32x2 __attribute__((ext_vector_type(2)));
typedef int i32x4 __attribute__((ext_vector_type(4)));

static __device__ __forceinline__ unsigned short f2bf(float f) {
  union { float f; unsigned int u; } v; v.f = f;
  unsigned int r = v.u + 0x7fffu + ((v.u >> 16) & 1u);  // RNE (finite values)
  return (unsigned short)(r >> 16);
}
static __device__ __forceinline__ float bf2f(unsigned short b) {
  union { unsigned int u; float f; } v; v.u = ((unsigned int)b) << 16;
  return v.f;
}

// ---------------- GEMM body (LDS-staged MFMA) ----------------
// hW_bf16[n,128] = h[n,128] @ W. 64 nodes/block, operand-swapped MFMA so
// each lane stores contiguous ushort4 runs of its own node row.
static __device__ __forceinline__ void gemm_body(
    int gblk, const float* __restrict__ h, const unsigned short* __restrict__ Wt,
    unsigned short* __restrict__ out, int n, unsigned short* lds) {
  int t = threadIdx.x;
  int block0 = gblk * 64;

  const f32x4* h4 = (const f32x4*)h;
  #pragma unroll
  for (int i = 0; i < 8; ++i) {
    int idx = t + 256 * i;          // 0..2047
    int r = idx >> 5, c = idx & 31; // row, float4-col
    int grow = block0 + r; if (grow >= n) grow = n - 1;
    f32x4 v = __builtin_nontemporal_load(&h4[(size_t)grow * 32 + c]);
    ushort4 b;
    b.x = f2bf(v.x); b.y = f2bf(v.y); b.z = f2bf(v.z); b.w = f2bf(v.w);
    *(ushort4*)&lds[r * LDSP + c * 4] = b;
  }
  __syncthreads();

  int lane = t & 63, wave = t >> 6;
  int row16 = lane & 15;
  int kgrp = lane >> 4;

  short8 afrag[4];
  #pragma unroll
  for (int ks = 0; ks < 4; ++ks)
    afrag[ks] =
        *(const short8*)&lds[(wave * 16 + row16) * LDSP + ks * 32 + kgrp * 8];

  f32x4 acc[8];
  #pragma unroll
  for (int ct = 0; ct < 8; ++ct) {
    acc[ct] = (f32x4){0.0f, 0.0f, 0.0f, 0.0f};
    const short8* wrow =
        (const short8*)(Wt + (size_t)(ct * 16 + row16) * NFEAT);
    #pragma unroll
    for (int ks = 0; ks < 4; ++ks) {
      acc[ct] = __builtin_amdgcn_mfma_f32_16x16x32_bf16(
          wrow[ks * 4 + kgrp], afrag[ks], acc[ct], 0, 0, 0);
    }
  }

  int orow = block0 + wave * 16 + row16;
  if (orow < n) {
    unsigned short* op = out + (size_t)orow * NFEAT + kgrp * 4;
    #pragma unroll
    for (int ct = 0; ct < 8; ++ct) {
      ushort4 o;
      o.x = f2bf(acc[ct][0]); o.y = f2bf(acc[ct][1]);
      o.z = f2bf(acc[ct][2]); o.w = f2bf(acc[ct][3]);
      *(ushort4*)(op + ct * 16) = o;
    }
  }
}

__global__ __launch_bounds__(256) void gemm_mfma_kernel(
    const float* __restrict__ h, const unsigned short* __restrict__ Wt,
    unsigned short* __restrict__ out, int n) {
  __shared__ int lds_i[64 * LDSP / 2];
  gemm_body(blockIdx.x, h, Wt, out, n, (unsigned short*)lds_i);
}

// gemm0 fused with Pass A (bucket histogram) — independent work.
__global__ __launch_bounds__(256) void fused_g0_hist_kernel(
    const float* __restrict__ x, const unsigned short* __restrict__ Wt0,
    unsigned short* __restrict__ hWb, int n, int gb,
    const int4* __restrict__ dst4, int* __restrict__ bcnt, int e4, int nbuc) {
  __shared__ int lds_i[64 * LDSP / 2];
  int t = threadIdx.x;
  if ((int)blockIdx.x < gb) {
    gemm_body(blockIdx.x, x, Wt0, hWb, n, (unsigned short*)lds_i);
  } else {
    int* hist = lds_i;
    hist[t] = 0;
    __syncthreads();
    int base = ((int)blockIdx.x - gb) * 1024;
    #pragma unroll
    for (int i = 0; i < 4; ++i) {
      int idx = base + t + 256 * i;
      if (idx < e4) {
        int4 d = dst4[idx];
        atomicAdd(&hist[d.x >> BSH], 1);
        atomicAdd(&hist[d.y >> BSH], 1);
        atomicAdd(&hist[d.z >> BSH], 1);
        atomicAdd(&hist[d.w >> BSH], 1);
      }
    }
    __syncthreads();
    int h = hist[t];
    if (t < nbuc && h) atomicAdd(&bcnt[t], h);
  }
}

// Pass B: exclusive scan of bucket counts (nbuc <= 256), init gcur, rowp[n]=E
__global__ __launch_bounds__(256) void scan_buckets_kernel(
    const int* __restrict__ bcnt, int* __restrict__ boff,
    int* __restrict__ gcur, int* __restrict__ rowp, int nbuc, int n, int e) {
  __shared__ int wsum[4];
  int t = threadIdx.x, lane = t & 63, wid = t >> 6;
  int v = (t < nbuc) ? bcnt[t] : 0;
  int s = v;
  #pragma unroll
  for (int off = 1; off < 64; off <<= 1) {
    int u = __shfl_up(s, off, 64);
    if (lane >= off) s += u;
  }
  if (lane == 63) wsum[wid] = s;
  __syncthreads();
  int add = 0;
  for (int w = 0; w < wid; ++w) add += wsum[w];
  int incl = add + s;
  if (t < nbuc) { boff[t] = incl - v; gcur[t] = incl - v; }
  if (t == nbuc - 1) boff[nbuc] = incl;  // == E
  if (t == 0) rowp[n] = e;
}

// Pass C: scatter (dst,src) u64 into bucket-major ebuf, block-chunked.
__global__ __launch_bounds__(256) void bucket_scatter_kernel(
    const int4* __restrict__ src4, const int4* __restrict__ dst4,
    int* __restrict__ gcur, unsigned long long* __restrict__ ebuf, int e4) {
  __shared__ int hist[256];
  __shared__ int cbase[256];
  __shared__ int cur[256];
  int t = threadIdx.x;
  hist[t] = 0; cur[t] = 0;
  __syncthreads();
  int base = blockIdx.x * 1024;
  int4 dv[4], sv[4];
  bool val[4];
  #pragma unroll
  for (int i = 0; i < 4; ++i) {
    int idx = base + t + 256 * i;
    val[i] = idx < e4;
    if (val[i]) {
      dv[i] = dst4[idx];
      sv[i] = src4[idx];
      atomicAdd(&hist[dv[i].x >> BSH], 1);
      atomicAdd(&hist[dv[i].y >> BSH], 1);
      atomicAdd(&hist[dv[i].z >> BSH], 1);
      atomicAdd(&hist[dv[i].w >> BSH], 1);
    }
  }
  __syncthreads();
  int h = hist[t];
  if (h) cbase[t] = atomicAdd(&gcur[t], h);  // hist[t]==0 for t>=nbuc
  __syncthreads();
  #pragma unroll
  for (int i = 0; i < 4; ++i) {
    if (val[i]) {
      int d, s, b, p;
      d = dv[i].x; s = sv[i].x; b = d >> BSH;
      p = cbase[b] + atomicAdd(&cur[b], 1);
      ebuf[p] = ((unsigned long long)(unsigned)d << 32) | (unsigned)s;
      d = dv[i].y; s = sv[i].y; b = d >> BSH;
      p = cbase[b] + atomicAdd(&cur[b], 1);
      ebuf[p] = ((unsigned long long)(unsigned)d << 32) | (unsigned)s;
      d = dv[i].z; s = sv[i].z; b = d >> BSH;
      p = cbase[b] + atomicAdd(&cur[b], 1);
      ebuf[p] = ((unsigned long long)(unsigned)d << 32) | (unsigned)s;
      d = dv[i].w; s = sv[i].w; b = d >> BSH;
      p = cbase[b] + atomicAdd(&cur[b], 1);
      ebuf[p] = ((unsigned long long)(unsigned)d << 32) | (unsigned)s;
    }
  }
}

// Pass D1: per-bucket degree hist (LDS) + local scan -> rowp, dinv.
__global__ __launch_bounds__(256) void bucket_deg_kernel(
    const unsigned long long* __restrict__ ebuf, const int* __restrict__ boff,
    int* __restrict__ rowp, float* __restrict__ dinv, int n) {
  __shared__ int deg[BWID];
  __shared__ int wsum[4];
  int t = threadIdx.x;
  int b = blockIdx.x, node0 = b << BSH;
  deg[t] = 0; deg[t + 256] = 0;
  __syncthreads();
  int ebeg = boff[b], eend = boff[b + 1];
  for (int i = ebeg + t; i < eend; i += 256) {
    int d = (int)(ebuf[i] >> 32);
    atomicAdd(&deg[d - node0], 1);
  }
  __syncthreads();
  int d0 = deg[2 * t], d1 = deg[2 * t + 1];
  int s = d0 + d1;
  int lane = t & 63, wid = t >> 6;
  int sc = s;
  #pragma unroll
  for (int off = 1; off < 64; off <<= 1) {
    int u = __shfl_up(sc, off, 64);
    if (lane >= off) sc += u;
  }
  if (lane == 63) wsum[wid] = sc;
  __syncthreads();
  int add = 0;
  for (int w = 0; w < wid; ++w) add += wsum[w];
  int excl = ebeg + add + sc - s;  // rowp of node 2t in this bucket
  int node = node0 + 2 * t;
  if (node < n) {
    rowp[node] = excl;
    dinv[node] = rsqrtf(1.0f + (float)d0);
  }
  if (node + 1 < n) {
    rowp[node + 1] = excl + d0;
    dinv[node + 1] = rsqrtf(1.0f + (float)d1);
  }
}

// Pass D2: per-bucket fine scatter into colw (writes confined to the
// bucket's ~32KB region -> one block/XCD -> L2 lines merge fully).
__global__ __launch_bounds__(256) void bucket_fill_kernel(
    const unsigned long long* __restrict__ ebuf, const int* __restrict__ boff,
    const int* __restrict__ rowp, const float* __restrict__ dinv,
    unsigned int* __restrict__ colw, int n) {
  __shared__ int cur[BWID];
  int t = threadIdx.x;
  int b = blockIdx.x, node0 = b << BSH;
  for (int k = t; k < BWID; k += 256) {
    int node = node0 + k;
    cur[k] = (node < n) ? rowp[node] : 0;
  }
  __syncthreads();
  int ebeg = boff[b], eend = boff[b + 1];
  for (int i = ebeg + t; i < eend; i += 256) {
    unsigned long long p = ebuf[i];
    int d = (int)(p >> 32);
    int s = (int)(unsigned int)p;
    float w = dinv[s] * dinv[d];
    unsigned int wq = (unsigned int)(w * 32767.0f + 0.5f);
    int pos = atomicAdd(&cur[d - node0], 1);
    colw[pos] = ((unsigned int)s << 15) | wq;
  }
}

// W fp32 [k][n] -> Wt bf16 [n][k]  (128x128), 3 weights in one launch
__global__ __launch_bounds__(256) void wprep_kernel(
    const float* __restrict__ W0, const float* __restrict__ W1,
    const float* __restrict__ W2, unsigned short* __restrict__ Wt0,
    unsigned short* __restrict__ Wt1, unsigned short* __restrict__ Wt2) {
  int which = blockIdx.x >> 6;
  int i = (blockIdx.x & 63) * 256 + threadIdx.x;
  int nn = i >> 7, k = i & 127;
  const float* W = which == 0 ? W0 : (which == 1 ? W1 : W2);
  unsigned short* Wt = which == 0 ? Wt0 : (which == 1 ? Wt1 : Wt2);
  Wt[nn * 128 + k] = f2bf(W[k * 128 + nn]);
}

// ---------------- Aggregate ----------------
// One wave per node, quarter-split gathers: lanes (q*16..q*16+15) handle
// edge j+4k+q; each lane loads 16B (dwordx4) of a row. Inner loop steps
// 16 edges issuing 4 independent gathers back-to-back (addresses all
// known after the chunk colw load) -> 4+ outstanding loads per wave.
// Lanes >= cnt carry pk=0 (row 0, weight 0): body runs unconditionally.
__global__ __launch_bounds__(256) void aggregate_kernel(
    const unsigned short* __restrict__ hWb, const int* __restrict__ row_ptr,
    const unsigned int* __restrict__ colw, const float* __restrict__ dinv,
    const float* __restrict__ bias, const float* __restrict__ resid,
    float* __restrict__ out, int n) {
  int node = blockIdx.x * 4 + (threadIdx.x >> 6);
  int lane = threadIdx.x & 63;
  if (node >= n) return;  // wave-uniform
  int q = lane >> 4;      // quarter: which edge of the 4-pack
  int l15 = lane & 15;
  int lb = l15 * 16;      // byte offset within a 256B row
  const char* hWbc = (const char*)hWb;
  int beg = row_ptr[node], end = row_ptr[node + 1];
  const float WQI = 1.0f / 32767.0f;

  // hoisted independent loads: self row word, bias, resid, dinv
  unsigned int su =
      *(const unsigned int*)(hWbc + (size_t)node * 256 + (unsigned)(lb + q * 4));
  f32x2 bv = ((const f32x2*)bias)[l15 * 4 + q];
  size_t oidx = (size_t)node * 64 + (unsigned)(l15 * 4 + q);
  f32x2 rv = (f32x2){0.0f, 0.0f};
  if (resid != nullptr)
    rv = __builtin_nontemporal_load(&((const f32x2*)resid)[oidx]);
  float di = dinv[node];

  f32x2 acc2[4];
  #pragma unroll
  for (int m = 0; m < 4; ++m) acc2[m] = (f32x2){0.0f, 0.0f};

  for (int cbeg = beg; cbeg < end; cbeg += 64) {
    int cnt = end - cbeg; if (cnt > 64) cnt = 64;
    unsigned int pk = 0;                 // lanes >= cnt: row 0, weight 0
    if (lane < cnt) pk = __builtin_nontemporal_load(&colw[cbeg + lane]);
    unsigned int bo = (pk >> 15) << 8;   // row byte offset (s * 256)
    float wv = (float)(pk & 0x7fffu) * WQI;
    for (int j = 0; j < cnt; j += 16) {
      unsigned int b0 = (unsigned int)__shfl((int)bo, j + 0 + q, 64);
      unsigned int b1 = (unsigned int)__shfl((int)bo, j + 4 + q, 64);
      unsigned int b2 = (unsigned int)__shfl((int)bo, j + 8 + q, 64);
      unsigned int b3 = (unsigned int)__shfl((int)bo, j + 12 + q, 64);
      float w0 = __shfl(wv, j + 0 + q, 64);
      float w1 = __shfl(wv, j + 4 + q, 64);
      float w2 = __shfl(wv, j + 8 + q, 64);
      float w3 = __shfl(wv, j + 12 + q, 64);
      // 4 independent gathers, issued back-to-back
      i32x4 p0 = *(const i32x4*)(hWbc + (b0 + (unsigned int)lb));
      i32x4 p1 = *(const i32x4*)(hWbc + (b1 + (unsigned int)lb));
      i32x4 p2 = *(const i32x4*)(hWbc + (b2 + (unsigned int)lb));
      i32x4 p3 = *(const i32x4*)(hWbc + (b3 + (unsigned int)lb));
      #pragma unroll
      for (int m = 0; m < 4; ++m) {
        int u = p0[m];
        f32x2 v;
        v.x = __int_as_float(u << 16);
        v.y = __int_as_float((int)(u & 0xffff0000));
        acc2[m] += (f32x2){w0, w0} * v;
      }
      #pragma unroll
      for (int m = 0; m < 4; ++m) {
        int u = p1[m];
        f32x2 v;
        v.x = __int_as_float(u << 16);
        v.y = __int_as_float((int)(u & 0xffff0000));
        acc2[m] += (f32x2){w1, w1} * v;
      }
      #pragma unroll
      for (int m = 0; m < 4; ++m) {
        int u = p2[m];
        f32x2 v;
        v.x = __int_as_float(u << 16);
        v.y = __int_as_float((int)(u & 0xffff0000));
        acc2[m] += (f32x2){w2, w2} * v;
      }
      #pragma unroll
      for (int m = 0; m < 4; ++m) {
        int u = p3[m];
        f32x2 v;
        v.x = __int_as_float(u << 16);
        v.y = __int_as_float((int)(u & 0xffff0000));
        acc2[m] += (f32x2){w3, w3} * v;
      }
    }
  }

  // reduce across the 4 quarters: all lanes end with full sums for their
  // 8 columns [l15*8, l15*8+8)
  #pragma unroll
  for (int m = 0; m < 4; ++m) {
    acc2[m].x += __shfl_xor(acc2[m].x, 16, 64);
    acc2[m].x += __shfl_xor(acc2[m].x, 32, 64);
    acc2[m].y += __shfl_xor(acc2[m].y, 16, 64);
    acc2[m].y += __shfl_xor(acc2[m].y, 32, 64);
  }

  // epilogue, all 64 lanes active: quarter q owns columns 2q, 2q+1 of
  // this lane's 8-column slice
  float sx = 0.0f, sy = 0.0f;
  #pragma unroll
  for (int k = 0; k < 4; ++k) {
    if (q == k) { sx = acc2[k].x; sy = acc2[k].y; }
  }
  float dii = di * di;
  float ax = sx + dii * __int_as_float((int)(su << 16)) + bv.x + rv.x;
  float ay = sy + dii * __int_as_float((int)(su & 0xffff0000u)) + bv.y + rv.y;
  f32x2 o;
  o.x = ax > 0.0f ? ax : expm1f(ax);
  o.y = ay > 0.0f ? ay : expm1f(ay);
  __builtin_nontemporal_store(o, &((f32x2*)out)[oidx]);
}

extern "C" void kernel_launch(void* const* d_in, const int* in_sizes, int n_in,
                              void* d_out, int out_size, void* d_ws, size_t ws_size,
                              hipStream_t stream) {
  const float* x  = (const float*)d_in[0];
  const int* eidx = (const int*)d_in[1];
  const float* W0 = (const float*)d_in[2];
  const float* b0 = (const float*)d_in[3];
  const float* W1 = (const float*)d_in[4];
  const float* b1 = (const float*)d_in[5];
  const float* W2 = (const float*)d_in[6];
  const float* b2 = (const float*)d_in[7];
  float* outp = (float*)d_out;

  const int N = in_sizes[0] / NFEAT;   // 100000
  const int E = in_sizes[1] / 2;       // 1600000 (divisible by 4)
  const int* src = eidx;
  const int* dst = eidx + E;
  const int NBUC = (N + BWID - 1) >> BSH;  // 196
  const int e4 = E / 4;

  // workspace layout (all chunk sizes 1KB-multiples)
  const size_t S1 = 401408;                   // > (N+1)*4
  const size_t SBK = 1024;                    // > (NBUC+1)*4
  const size_t SW = 32768;                    // 128*128*2
  const size_t SE = (size_t)E * 4;            // 6.4 MB packed edges
  const size_t SEB = (size_t)E * 8;           // 12.8 MB bucketed (dst,src)
  const size_t SH = (size_t)N * NFEAT * 2;    // 25.6 MB bf16 features
  const size_t SF = (size_t)N * NFEAT * 4;    // 51.2 MB fp32 features
  char* p = (char*)d_ws;
  float* dinv   = (float*)p;            p += S1;
  int*   rowp   = (int*)p;              p += S1;
  int*   bcnt   = (int*)p;              p += SBK;
  int*   boff   = (int*)p;              p += SBK;
  int*   gcur   = (int*)p;              p += SBK;
  unsigned short* Wt0 = (unsigned short*)p;  p += SW;
  unsigned short* Wt1 = (unsigned short*)p;  p += SW;
  unsigned short* Wt2 = (unsigned short*)p;  p += SW;
  unsigned int* colw = (unsigned int*)p; p += SE;
  unsigned long long* ebuf = (unsigned long long*)p; p += SEB;
  unsigned short* hWb = (unsigned short*)p;  p += SH;
  float* hA     = (float*)p;            p += SF;
  float* hB     = (float*)p;            p += SF;

  int gemm_blocks = (N + 63) / 64;        // 1563
  int cbk = (e4 + 1023) / 1024;           // 391 (4096 edges/block)
  int agg_blocks = (N + 3) / 4;

  // ---- prep + fused {gemm0, Pass A} ----
  wprep_kernel<<<192, 256, 0, stream>>>(W0, W1, W2, Wt0, Wt1, Wt2);
  hipMemsetAsync(bcnt, 0, (size_t)NBUC * 4, stream);
  fused_g0_hist_kernel<<<gemm_blocks + cbk, 256, 0, stream>>>(
      x, Wt0, hWb, N, gemm_blocks, (const int4*)dst, bcnt, e4, NBUC);

  // ---- bucketed CSR build ----
  scan_buckets_kernel<<<1, 256, 0, stream>>>(bcnt, boff, gcur, rowp,
                                             NBUC, N, E);
  bucket_scatter_kernel<<<cbk, 256, 0, stream>>>(
      (const int4*)src, (const int4*)dst, gcur, ebuf, e4);
  bucket_deg_kernel<<<NBUC, 256, 0, stream>>>(ebuf, boff, rowp, dinv, N);
  bucket_fill_kernel<<<NBUC, 256, 0, stream>>>(ebuf, boff, rowp, dinv,
                                               colw, N);

  // ---- layer 0 aggregate (gemm0 already done) ----
  aggregate_kernel<<<agg_blocks, 256, 0, stream>>>(hWb, rowp, colw, dinv,
                                                   b0, nullptr, hA, N);
  // ---- layer 1 ----
  gemm_mfma_kernel<<<gemm_blocks, 256, 0, stream>>>(hA, Wt1, hWb, N);
  aggregate_kernel<<<agg_blocks, 256, 0, stream>>>(hWb, rowp, colw, dinv,
                                                   b1, hA, hB, N);
  // ---- layer 2, write d_out ----
  gemm_mfma_kernel<<<gemm_blocks, 256, 0, stream>>>(hB, Wt2, hWb, N);
  aggregate_kernel<<<agg_blocks, 256, 0, stream>>>(hWb, rowp, colw, dinv,
                                                   b2, hB, outp, N);
}